// Round 1
// baseline (1216.136 us; speedup 1.0000x reference)
//
#include <hip/hip_runtime.h>

// NerfModel: voxel-grid gather + SH-deg2 eval.
//   inputs : x (M,3) f32, d (M,3) f32, voxel_grid (200,200,200,28) f32
//   outputs: color (M,3) f32 then sigma (M,) f32, concatenated in d_out.
//
// The 896 MB grid >> 256 MB L3, so the masked random 112 B gather was running at
// ~0.5 TB/s effective (random-row DRAM regime). This version bucket-sorts the
// masked points by i0 slab first (count -> scan -> scatter, LDS histograms, no
// global atomics), then gathers over the bucket-sorted list: the concurrent
// gather window's grid footprint (~110-200 MB) becomes L3-resident and each
// grid line is fetched from HBM ~once.

constexpr float kScale = 1.5f;
constexpr int   kN     = 200;
constexpr int   kNB    = 256;    // buckets = i0 slab (200 used)
constexpr int   kNBLK  = 2048;   // fixed block count for count/scatter passes
constexpr int   kBT    = 256;    // threads per block

__device__ __forceinline__ bool point_to_voxel(float x0, float x1, float x2,
                                               int& bucket, int& voff) {
    const bool mask = (fabsf(x0) < kScale) && (fabsf(x1) < kScale) && (fabsf(x2) < kScale);
    if (!mask) return false;
    // idx = clip((int)(x / (2*SCALE/N) + N/2), 0, N-1); same formula as the
    // verified-passing kernel (truncation == astype(int32) since arg > 0 under mask).
    const float h = 2.0f * kScale / (float)kN;   // 0.015f
    int i0 = (int)(x0 / h + 0.5f * (float)kN);
    int i1 = (int)(x1 / h + 0.5f * (float)kN);
    int i2 = (int)(x2 / h + 0.5f * (float)kN);
    i0 = min(max(i0, 0), kN - 1);
    i1 = min(max(i1, 0), kN - 1);
    i2 = min(max(i2, 0), kN - 1);
    bucket = i0;
    voff   = (i0 * kN + i1) * kN + i2;
    return true;
}

// ---- Pass 1: per-block bucket histogram; zero outputs for unmasked points ----
__global__ __launch_bounds__(kBT) void k_count(const float* __restrict__ x,
                                               float* __restrict__ out, int M,
                                               int* __restrict__ ghist) {
    __shared__ int h[kNB];
    for (int t = threadIdx.x; t < kNB; t += kBT) h[t] = 0;
    __syncthreads();
    const int stride = kNBLK * kBT;
    for (int i = blockIdx.x * kBT + threadIdx.x; i < M; i += stride) {
        const float x0 = x[3 * i + 0];
        const float x1 = x[3 * i + 1];
        const float x2 = x[3 * i + 2];
        int b, voff;
        if (point_to_voxel(x0, x1, x2, b, voff)) {
            atomicAdd(&h[b], 1);
        } else {
            out[3 * i + 0] = 0.0f;
            out[3 * i + 1] = 0.0f;
            out[3 * i + 2] = 0.0f;
            out[(size_t)3 * M + i] = 0.0f;
        }
    }
    __syncthreads();
    for (int t = threadIdx.x; t < kNB; t += kBT) ghist[blockIdx.x * kNB + t] = h[t];
}

// ---- Pass 2: per-bucket exclusive scan across blocks (one block per bucket) ----
__global__ __launch_bounds__(kBT) void k_scan_blocks(int* __restrict__ ghist,
                                                     int* __restrict__ totals) {
    const int b = blockIdx.x;
    __shared__ int sums[kBT];
    constexpr int per = kNBLK / kBT;   // 8
    const int base = threadIdx.x * per;
    int local[per];
    int s = 0;
    for (int k = 0; k < per; ++k) { local[k] = ghist[(base + k) * kNB + b]; s += local[k]; }
    sums[threadIdx.x] = s;
    __syncthreads();
    for (int off = 1; off < kBT; off <<= 1) {           // Hillis-Steele inclusive
        int t = (threadIdx.x >= off) ? sums[threadIdx.x - off] : 0;
        __syncthreads();
        sums[threadIdx.x] += t;
        __syncthreads();
    }
    int run = sums[threadIdx.x] - s;                    // exclusive base for this chunk
    for (int k = 0; k < per; ++k) { const int c = local[k]; ghist[(base + k) * kNB + b] = run; run += c; }
    if (threadIdx.x == kBT - 1) totals[b] = sums[kBT - 1];
}

// ---- Pass 3: exclusive scan of bucket totals -> bucket bases (+ grand total) ----
__global__ __launch_bounds__(kNB) void k_scan_buckets(const int* __restrict__ totals,
                                                      int* __restrict__ bases) {
    __shared__ int s[kNB];
    const int t = threadIdx.x;
    const int own = totals[t];
    s[t] = own;
    __syncthreads();
    for (int off = 1; off < kNB; off <<= 1) {
        int v = (t >= off) ? s[t - off] : 0;
        __syncthreads();
        s[t] += v;
        __syncthreads();
    }
    bases[t] = s[t] - own;
    if (t == kNB - 1) bases[kNB] = s[kNB - 1];          // Mc = total masked count
}

// ---- Pass 4: scatter masked points into bucket-sorted compacted arrays ----
__global__ __launch_bounds__(kBT) void k_scatter(const float* __restrict__ x,
                                                 const float* __restrict__ dir, int M,
                                                 const int* __restrict__ ghist,
                                                 const int* __restrict__ bases,
                                                 float4* __restrict__ payload,
                                                 int* __restrict__ voxarr) {
    __shared__ int cur[kNB];
    for (int t = threadIdx.x; t < kNB; t += kBT) cur[t] = 0;
    __syncthreads();
    const int stride = kNBLK * kBT;
    for (int i = blockIdx.x * kBT + threadIdx.x; i < M; i += stride) {
        const float x0 = x[3 * i + 0];
        const float x1 = x[3 * i + 1];
        const float x2 = x[3 * i + 2];
        int b, voff;
        if (point_to_voxel(x0, x1, x2, b, voff)) {
            const int r   = atomicAdd(&cur[b], 1);      // rank within (block, bucket)
            const int pos = bases[b] + ghist[blockIdx.x * kNB + b] + r;
            payload[pos] = make_float4(dir[3 * i + 0], dir[3 * i + 1], dir[3 * i + 2],
                                       __int_as_float(i));
            voxarr[pos] = voff;
        }
    }
}

// ---- Pass 5: locality-friendly gather + SH eval over the sorted list ----
__global__ __launch_bounds__(kBT) void k_gather(const float4* __restrict__ payload,
                                                const int* __restrict__ voxarr,
                                                const float* __restrict__ grid,
                                                float* __restrict__ out, int M,
                                                const int* __restrict__ bases) {
    const int j = blockIdx.x * kBT + threadIdx.x;
    if (j >= bases[kNB]) return;

    const float4 p = payload[j];
    const int i = __float_as_int(p.w);
    const size_t voff = (size_t)voxarr[j] * 28u;
    const float4* __restrict__ g4 = reinterpret_cast<const float4*>(grid + voff);
    const float4 t0 = g4[0];
    const float4 t1 = g4[1];
    const float4 t2 = g4[2];
    const float4 t3 = g4[3];
    const float4 t4 = g4[4];
    const float4 t5 = g4[5];
    const float4 t6 = g4[6];
    const float t[28] = {
        t0.x, t0.y, t0.z, t0.w,
        t1.x, t1.y, t1.z, t1.w,
        t2.x, t2.y, t2.z, t2.w,
        t3.x, t3.y, t3.z, t3.w,
        t4.x, t4.y, t4.z, t4.w,
        t5.x, t5.y, t5.z, t5.w,
        t6.x, t6.y, t6.z, t6.w
    };

    const float sg = fmaxf(t[0], 0.0f);

    const float dx = p.x, dy = p.y, dz = p.z;
    const float b0 = 0.282095f;
    const float b1 = -0.488603f * dy;
    const float b2 =  0.488603f * dz;
    const float b3 = -0.488603f * dx;
    const float b4 =  1.092548f * dx * dy;
    const float b5 = -1.092548f * dy * dz;
    const float b6 =  0.315392f * (2.0f * dz * dz - dx * dx - dy * dy);
    const float b7 = -1.092548f * dx * dz;
    const float b8 =  0.546274f * (dx * dx - dy * dy);

    const float c0 = b0 * t[1]  + b1 * t[2]  + b2 * t[3]  + b3 * t[4]  + b4 * t[5]
                   + b5 * t[6]  + b6 * t[7]  + b7 * t[8]  + b8 * t[9];
    const float c1 = b0 * t[10] + b1 * t[11] + b2 * t[12] + b3 * t[13] + b4 * t[14]
                   + b5 * t[15] + b6 * t[16] + b7 * t[17] + b8 * t[18];
    const float c2 = b0 * t[19] + b1 * t[20] + b2 * t[21] + b3 * t[22] + b4 * t[23]
                   + b5 * t[24] + b6 * t[25] + b7 * t[26] + b8 * t[27];

    out[3 * i + 0] = c0;
    out[3 * i + 1] = c1;
    out[3 * i + 2] = c2;
    out[(size_t)3 * M + i] = sg;
}

// ---- Fallback: the previous verified single-kernel path (ws too small) ----
__global__ __launch_bounds__(kBT) void nerf_fwd(
    const float* __restrict__ x,
    const float* __restrict__ dir,
    const float* __restrict__ grid,
    float* __restrict__ out, int M)
{
    int i = blockIdx.x * blockDim.x + threadIdx.x;
    if (i >= M) return;

    const float x0 = x[3 * i + 0];
    const float x1 = x[3 * i + 1];
    const float x2 = x[3 * i + 2];

    float c0 = 0.0f, c1 = 0.0f, c2 = 0.0f, sg = 0.0f;
    int b, voff;
    if (point_to_voxel(x0, x1, x2, b, voff)) {
        const float4* __restrict__ g4 = reinterpret_cast<const float4*>(grid + (size_t)voff * 28u);
        const float4 t0 = g4[0], t1 = g4[1], t2 = g4[2], t3 = g4[3], t4 = g4[4], t5 = g4[5], t6 = g4[6];
        const float t[28] = {
            t0.x, t0.y, t0.z, t0.w, t1.x, t1.y, t1.z, t1.w, t2.x, t2.y, t2.z, t2.w,
            t3.x, t3.y, t3.z, t3.w, t4.x, t4.y, t4.z, t4.w, t5.x, t5.y, t5.z, t5.w,
            t6.x, t6.y, t6.z, t6.w
        };
        sg = fmaxf(t[0], 0.0f);
        const float dx = dir[3 * i + 0], dy = dir[3 * i + 1], dz = dir[3 * i + 2];
        const float b0 = 0.282095f;
        const float b1 = -0.488603f * dy;
        const float b2 =  0.488603f * dz;
        const float b3 = -0.488603f * dx;
        const float b4 =  1.092548f * dx * dy;
        const float b5 = -1.092548f * dy * dz;
        const float b6 =  0.315392f * (2.0f * dz * dz - dx * dx - dy * dy);
        const float b7 = -1.092548f * dx * dz;
        const float b8 =  0.546274f * (dx * dx - dy * dy);
        c0 = b0*t[1]  + b1*t[2]  + b2*t[3]  + b3*t[4]  + b4*t[5]  + b5*t[6]  + b6*t[7]  + b7*t[8]  + b8*t[9];
        c1 = b0*t[10] + b1*t[11] + b2*t[12] + b3*t[13] + b4*t[14] + b5*t[15] + b6*t[16] + b7*t[17] + b8*t[18];
        c2 = b0*t[19] + b1*t[20] + b2*t[21] + b3*t[22] + b4*t[23] + b5*t[24] + b6*t[25] + b7*t[26] + b8*t[27];
    }
    out[3 * i + 0] = c0;
    out[3 * i + 1] = c1;
    out[3 * i + 2] = c2;
    out[(size_t)3 * M + i] = sg;
}

extern "C" void kernel_launch(void* const* d_in, const int* in_sizes, int n_in,
                              void* d_out, int out_size, void* d_ws, size_t ws_size,
                              hipStream_t stream) {
    const float* x    = (const float*)d_in[0];
    const float* dir  = (const float*)d_in[1];
    const float* grid = (const float*)d_in[2];
    float* out = (float*)d_out;

    const int M = in_sizes[0] / 3;   // 4194304

    // Workspace layout: payload (M float4) | voxarr (M int) | ghist (kNBLK*kNB int)
    //                   | totals (kNB int) | bases (kNB+1 int)   ~= 86 MB
    const size_t need = (size_t)M * 16 + (size_t)M * 4
                      + (size_t)kNBLK * kNB * 4 + (size_t)(2 * kNB + 1) * 4;
    if (d_ws == nullptr || ws_size < need) {
        const int grid_dim = (M + kBT - 1) / kBT;
        nerf_fwd<<<grid_dim, kBT, 0, stream>>>(x, dir, grid, out, M);
        return;
    }

    float4* payload = (float4*)d_ws;
    int* voxarr = (int*)(payload + M);
    int* ghist  = voxarr + M;
    int* totals = ghist + (size_t)kNBLK * kNB;
    int* bases  = totals + kNB;

    k_count      <<<kNBLK, kBT, 0, stream>>>(x, out, M, ghist);
    k_scan_blocks<<<kNB,   kBT, 0, stream>>>(ghist, totals);
    k_scan_buckets<<<1,    kNB, 0, stream>>>(totals, bases);
    k_scatter    <<<kNBLK, kBT, 0, stream>>>(x, dir, M, ghist, bases, payload, voxarr);
    k_gather     <<<(M + kBT - 1) / kBT, kBT, 0, stream>>>(payload, voxarr, grid, out, M, bases);
}